// Round 1
// 216.935 us; speedup vs baseline: 1.0068x; 1.0068x over previous
//
#include <hip/hip_runtime.h>

#define T_SEQ 2048
#define NHEAD 16
#define HD 64
#define CDIM 1024

typedef __bf16 bf16x8 __attribute__((ext_vector_type(8)));
typedef float f32x4 __attribute__((ext_vector_type(4)));

union U16x8 { uint4 u4; unsigned short s[8]; bf16x8 b; };

__device__ __forceinline__ float bf2f(unsigned short u) {
    return __uint_as_float(((unsigned int)u) << 16);
}
__device__ __forceinline__ unsigned short f2bf(float f) {
    unsigned int u = __float_as_uint(f);
    u += 0x7fffu + ((u >> 16) & 1u);   // round-to-nearest-even
    return (unsigned short)(u >> 16);
}
__device__ __forceinline__ unsigned short f2bf_fast(float f) {   // round-half-up
    return (unsigned short)((__float_as_uint(f) + 0x8000u) >> 16);
}
__device__ __forceinline__ U16x8 load8f(const float* __restrict__ p) {
    U16x8 r;
    float4 f0 = *(const float4*)p;
    float4 f1 = *(const float4*)(p + 4);
    r.s[0] = f2bf(f0.x); r.s[1] = f2bf(f0.y); r.s[2] = f2bf(f0.z); r.s[3] = f2bf(f0.w);
    r.s[4] = f2bf(f1.x); r.s[5] = f2bf(f1.y); r.s[6] = f2bf(f1.z); r.s[7] = f2bf(f1.w);
    return r;
}

// async global->LDS, 16 B per lane; LDS dest = wave-uniform base + lane*16
__device__ __forceinline__ void async_copy16(const unsigned short* g, unsigned short* l) {
    __builtin_amdgcn_global_load_lds(
        (const __attribute__((address_space(1))) unsigned int*)g,
        (__attribute__((address_space(3))) unsigned int*)l, 16, 0, 0);
}

#define LOG2E 1.442695040f

// raw barrier / counted waits (NEVER __syncthreads in the 8-phase loop: it drains vmcnt)
#define BAR()    asm volatile("s_barrier" ::: "memory")
#define LGKM0()  asm volatile("s_waitcnt lgkmcnt(0)" ::: "memory")
#define VMC6()   asm volatile("s_waitcnt vmcnt(6)" ::: "memory")
#define VMC0()   asm volatile("s_waitcnt vmcnt(0)" ::: "memory")

// ---------------------------------------------------------------------------
// Conversion pass
// ---------------------------------------------------------------------------
__global__ __launch_bounds__(256) void conv_bf16(
    const float* __restrict__ in, unsigned short* __restrict__ out, int n)
{
    const int i = (blockIdx.x * 256 + threadIdx.x) * 8;
    if (i < n) {
        U16x8 o = load8f(&in[i]);
        *(uint4*)&out[i] = o.u4;
    }
}

// in: [R,C] fp32 -> out: [C,R] bf16.  R,C multiples of 64.
__global__ __launch_bounds__(256) void transpose_conv(
    const float* __restrict__ in, unsigned short* __restrict__ out, int R, int C)
{
    __shared__ float tile[64][65];
    const int r0 = blockIdx.x * 64;
    const int c0 = blockIdx.y * 64;
    const int tid = threadIdx.x;
    const int rr = tid >> 4;
    const int cc = (tid & 15) * 4;
#pragma unroll
    for (int p = 0; p < 4; ++p) {
        float4 v = *(const float4*)&in[(size_t)(r0 + p * 16 + rr) * C + c0 + cc];
        tile[p * 16 + rr][cc] = v.x;
        tile[p * 16 + rr][cc + 1] = v.y;
        tile[p * 16 + rr][cc + 2] = v.z;
        tile[p * 16 + rr][cc + 3] = v.w;
    }
    __syncthreads();
    const int n = tid >> 2;
    const int s = (tid & 3) * 8;
#pragma unroll
    for (int p = 0; p < 2; ++p) {
        const int k = s + p * 32;
        U16x8 o;
#pragma unroll
        for (int j = 0; j < 8; ++j) o.s[j] = f2bf(tile[k + j][n]);
        *(uint4*)&out[(size_t)(c0 + n) * R + r0 + k] = o.u4;
    }
}

// ---------------------------------------------------------------------------
// m97-style GEMM core (kept for proj): C[128x128] = A[M,K] * Bt[N,K]^T
// ---------------------------------------------------------------------------
__device__ __forceinline__ void gemm128_core(
    const unsigned short* __restrict__ A,
    const unsigned short* __restrict__ Bt,
    int K, int m0, int n0,
    unsigned short* As, unsigned short* Bs, f32x4 acc[4][4])
{
    const int tid = threadIdx.x;
    const int w = tid >> 6, lane = tid & 63;
    const int ln = lane & 15, quad = lane >> 4;
    const int wm = w >> 1, wn = w & 1;
    const int lr = lane >> 3;        // 0..7
    const int lc = (lane & 7) * 8;   // col start (elems)

    for (int kb = 0; kb < K; kb += 64) {
        __syncthreads();
#pragma unroll
        for (int i = 0; i < 4; ++i) {
            async_copy16(&A[(size_t)(m0 + w * 32 + i * 8 + lr) * K + kb + lc],
                         &As[(w * 32 + i * 8) * 64]);
            async_copy16(&Bt[(size_t)(n0 + w * 32 + i * 8 + lr) * K + kb + lc],
                         &Bs[(w * 32 + i * 8) * 64]);
        }
        __syncthreads();
#pragma unroll
        for (int kk = 0; kk < 2; ++kk) {
            U16x8 af[4], bff[4];
#pragma unroll
            for (int i = 0; i < 4; ++i)
                af[i].u4 = *(const uint4*)&As[(wm * 64 + i * 16 + ln) * 64 + kk * 32 + quad * 8];
#pragma unroll
            for (int j = 0; j < 4; ++j)
                bff[j].u4 = *(const uint4*)&Bs[(wn * 64 + j * 16 + ln) * 64 + kk * 32 + quad * 8];
#pragma unroll
            for (int i = 0; i < 4; ++i)
#pragma unroll
                for (int j = 0; j < 4; ++j)
                    acc[i][j] = __builtin_amdgcn_mfma_f32_16x16x32_bf16(af[i].b, bff[j].b, acc[i][j], 0, 0, 0);
        }
    }
}

// ---------------------------------------------------------------------------
// 256x256 8-phase counted-vmcnt GEMM (T2+T3+T4+T5), fused QKV epilogue.
//   One uniform GEMM: C[4096 tokens x 3072 chans] = Xb * Wqkvt^T.
//   BM=BN=256, BK=64, 512 thr = 8 waves (2M x 4N), per-wave C = 128x64.
//   LDS 128 KiB: A/B double-buffered by K-tile parity, st_16x32 swizzle
//   (byte ^= ((byte>>9)&1)<<5, i.e. flip bit5 when row&4) applied on the
//   pre-swizzled global SOURCE (global_load_lds writes LDS linearly) and on
//   every ds_read address.
//   Staging units per K-tile: [A-qm0, B-qn0, B-qn1, A-qn1-rows], each 16 KB
//   = 2 global_load_lds/wave; one unit per phase, region freed exactly one
//   phase before its overwrite (B-frags register-cached across qm phases).
//   vmcnt(6) at phases 4/8 only (3 units = 6 loads stay in flight).
// ---------------------------------------------------------------------------

// stage A unit (0: rows {0-63,128-191}, 1: rows {64-127,192-255}) of K-tile t
__device__ __forceinline__ void stageA(const unsigned short* __restrict__ A,
                                       unsigned short* buf,
                                       int m0, int t, int unit, int w, int lane)
{
#pragma unroll
    for (int s = 0; s < 2; ++s) {
        const int r0 = s * 128 + unit * 64 + w * 8;          // wave-uniform
        const int row = r0 + (lane >> 3);
        const int col = (16 * (lane & 7)) ^ ((row & 4) ? 32 : 0);  // bytes, pre-swizzled src
        const unsigned short* src = A + (size_t)(m0 + row) * CDIM + t * 64 + (col >> 1);
        async_copy16(src, buf + r0 * 64);                    // linear LDS dest
    }
}

// stage B unit (0: qn0 rows {wn*64+0..31}, 1: qn1 rows {wn*64+32..63}) of tile t
__device__ __forceinline__ void stageB(const unsigned short* __restrict__ B,
                                       unsigned short* buf,
                                       int n0, int t, int unit, int w, int lane)
{
#pragma unroll
    for (int s = 0; s < 2; ++s) {
        const int slice = s * 8 + w;
        const int r0 = (slice >> 2) * 64 + unit * 32 + (slice & 3) * 8;  // wave-uniform
        const int row = r0 + (lane >> 3);
        const int col = (16 * (lane & 7)) ^ ((row & 4) ? 32 : 0);
        const unsigned short* src = B + (size_t)(n0 + row) * CDIM + t * 64 + (col >> 1);
        async_copy16(src, buf + r0 * 64);
    }
}

__device__ __forceinline__ void readA(U16x8 af[4][2], const unsigned short* buf,
                                      int wm, int qm, int ln, int quad)
{
#pragma unroll
    for (int i = 0; i < 4; ++i) {
        const int row = wm * 128 + qm * 64 + i * 16 + ln;
        const int sw = (row & 4) ? 32 : 0;
#pragma unroll
        for (int kk = 0; kk < 2; ++kk) {
            const int byt = row * 128 + ((kk * 64 + quad * 16) ^ sw);
            af[i][kk].u4 = *(const uint4*)((const char*)buf + byt);
        }
    }
}

__device__ __forceinline__ void readB(U16x8 bf[2][2], const unsigned short* buf,
                                      int wn, int qn, int ln, int quad)
{
#pragma unroll
    for (int jj = 0; jj < 2; ++jj) {
        const int row = wn * 64 + qn * 32 + jj * 16 + ln;
        const int sw = (row & 4) ? 32 : 0;
#pragma unroll
        for (int kk = 0; kk < 2; ++kk) {
            const int byt = row * 128 + ((kk * 64 + quad * 16) ^ sw);
            bf[jj][kk].u4 = *(const uint4*)((const char*)buf + byt);
        }
    }
}

template<int QM, int QN>
__device__ __forceinline__ void mfma16(f32x4 acc[8][4], const U16x8 af[4][2],
                                       const U16x8 bf[2][2])
{
    __builtin_amdgcn_s_setprio(1);
#pragma unroll
    for (int i = 0; i < 4; ++i)
#pragma unroll
        for (int jj = 0; jj < 2; ++jj)
#pragma unroll
            for (int kk = 0; kk < 2; ++kk)
                acc[QM * 4 + i][QN * 2 + jj] = __builtin_amdgcn_mfma_f32_16x16x32_bf16(
                    af[i][kk].b, bf[jj][kk].b, acc[QM * 4 + i][QN * 2 + jj], 0, 0, 0);
    __builtin_amdgcn_s_setprio(0);
}

__global__ __launch_bounds__(512) void qkv8(
    const unsigned short* __restrict__ Xb,    // [4096,1024] bf16
    const unsigned short* __restrict__ Wt,    // [3072,1024] bf16 (W^T; V rows at 2048)
    const float* __restrict__ bias,           // [3072]
    unsigned short* __restrict__ Qp,
    unsigned short* __restrict__ Kp,
    unsigned short* __restrict__ Vtp)         // [B,1024,T]
{
    __shared__ __align__(1024) unsigned short smem[4][16384];  // Abuf0,Abuf1,Bbuf0,Bbuf1
    unsigned short* Ab0 = smem[0];
    unsigned short* Ab1 = smem[1];
    unsigned short* Bb0 = smem[2];
    unsigned short* Bb1 = smem[3];

    const int tid = threadIdx.x;
    const int w = tid >> 6, lane = tid & 63;
    const int ln = lane & 15, quad = lane >> 4;
    const int wm = w >> 2, wn = w & 3;

    // bijective XCD swizzle (192 % 8 == 0): 24 consecutive tiles per XCD
    const int bid = blockIdx.x;
    const int swz = (bid & 7) * 24 + (bid >> 3);
    const int nt = swz % 12, mt = swz / 12;
    const int m0 = mt * 256, n0 = nt * 256;

    f32x4 acc[8][4];
#pragma unroll
    for (int i = 0; i < 8; ++i)
#pragma unroll
        for (int j = 0; j < 4; ++j) acc[i][j] = (f32x4){0.f, 0.f, 0.f, 0.f};

    // ---- prologue: 7 units (tile 0 complete + tile 1 A0/B0/B1), depth-3 pipe
    stageA(Xb, Ab0, m0, 0, 0, w, lane);
    stageB(Wt, Bb0, n0, 0, 0, w, lane);
    stageB(Wt, Bb0, n0, 0, 1, w, lane);
    stageA(Xb, Ab0, m0, 0, 1, w, lane);
    stageA(Xb, Ab1, m0, 1, 0, w, lane);
    stageB(Wt, Bb1, n0, 1, 0, w, lane);
    stageB(Wt, Bb1, n0, 1, 1, w, lane);
    VMC6();            // oldest 4 units (= tile 0) landed
    BAR();

    U16x8 af[4][2], bq0[2][2], bq1[2][2];

    // ---- main loop: 7 iters x 2 K-tiles; tiles 0..13
    for (int j = 0; j < 7; ++j) {
        const int e = 2 * j, o = 2 * j + 1;
        // P1: quad(0,0) of tile e  | stage A1(o) -> buf1
        readA(af, Ab0, wm, 0, ln, quad);
        readB(bq0, Bb0, wn, 0, ln, quad);
        stageA(Xb, Ab1, m0, o, 1, w, lane);
        BAR(); LGKM0();
        mfma16<0, 0>(acc, af, bq0);
        LGKM0(); BAR();
        // P2: quad(0,1)            | stage A0(e+2) -> buf0
        readB(bq1, Bb0, wn, 1, ln, quad);
        stageA(Xb, Ab0, m0, e + 2, 0, w, lane);
        BAR(); LGKM0();
        mfma16<0, 1>(acc, af, bq1);
        LGKM0(); BAR();
        // P3: quad(1,0)            | stage B0(e+2)
        readA(af, Ab0, wm, 1, ln, quad);
        stageB(Wt, Bb0, n0, e + 2, 0, w, lane);
        BAR(); LGKM0();
        mfma16<1, 0>(acc, af, bq0);
        LGKM0(); BAR();
        // P4: quad(1,1)            | stage B1(e+2) ; counted wait
        stageB(Wt, Bb0, n0, e + 2, 1, w, lane);
        BAR();
        mfma16<1, 1>(acc, af, bq1);
        VMC6(); BAR();
        // P5: quad(0,0) of tile o  | stage A1(e+2) -> buf0
        readA(af, Ab1, wm, 0, ln, quad);
        readB(bq0, Bb1, wn, 0, ln, quad);
        stageA(Xb, Ab0, m0, e + 2, 1, w, lane);
        BAR(); LGKM0();
        mfma16<0, 0>(acc, af, bq0);
        LGKM0(); BAR();
        // P6: quad(0,1)            | stage A0(o+2) -> buf1
        readB(bq1, Bb1, wn, 1, ln, quad);
        stageA(Xb, Ab1, m0, o + 2, 0, w, lane);
        BAR(); LGKM0();
        mfma16<0, 1>(acc, af, bq1);
        LGKM0(); BAR();
        // P7: quad(1,0)            | stage B0(o+2)
        readA(af, Ab1, wm, 1, ln, quad);
        stageB(Wt, Bb1, n0, o + 2, 0, w, lane);
        BAR(); LGKM0();
        mfma16<1, 0>(acc, af, bq0);
        LGKM0(); BAR();
        // P8: quad(1,1)            | stage B1(o+2) ; counted wait
        stageB(Wt, Bb1, n0, o + 2, 1, w, lane);
        BAR();
        mfma16<1, 1>(acc, af, bq1);
        VMC6(); BAR();
    }

    // ---- epilogue: tiles 14 (buf0), 15 (buf1); stage last unit then drain
    stageA(Xb, Ab1, m0, 15, 1, w, lane);
    VMC0(); BAR();

    readA(af, Ab0, wm, 0, ln, quad);
    readB(bq0, Bb0, wn, 0, ln, quad);
    readB(bq1, Bb0, wn, 1, ln, quad);
    mfma16<0, 0>(acc, af, bq0);
    mfma16<0, 1>(acc, af, bq1);
    readA(af, Ab0, wm, 1, ln, quad);
    mfma16<1, 0>(acc, af, bq0);
    mfma16<1, 1>(acc, af, bq1);

    readA(af, Ab1, wm, 0, ln, quad);
    readB(bq0, Bb1, wn, 0, ln, quad);
    readB(bq1, Bb1, wn, 1, ln, quad);
    mfma16<0, 0>(acc, af, bq0);
    mfma16<0, 1>(acc, af, bq1);
    readA(af, Ab1, wm, 1, ln, quad);
    mfma16<1, 0>(acc, af, bq0);
    mfma16<1, 1>(acc, af, bq1);

    // ---- C epilogue: n-tile selects Q / K / V^T (BN=256 divides 1024)
    const int which = n0 >> 10;
    float bv[4];
#pragma unroll
    for (int jj = 0; jj < 4; ++jj) bv[jj] = bias[n0 + wn * 64 + jj * 16 + ln];

    if (which < 2) {
        unsigned short* dst = (which == 0) ? Qp : Kp;
#pragma unroll
        for (int jj = 0; jj < 4; ++jj) {
            const int n = n0 + wn * 64 + jj * 16 + ln;
            const int h = (n >> 6) & 15, d = n & 63;
#pragma unroll
            for (int i = 0; i < 8; ++i)
#pragma unroll
                for (int r = 0; r < 4; ++r) {
                    const int m = m0 + wm * 128 + i * 16 + quad * 4 + r;
                    const int b = m >> 11, tt = m & 2047;
                    dst[(((size_t)(b * NHEAD + h) * T_SEQ) + tt) * HD + d] =
                        f2bf(acc[i][jj][r] + bv[jj]);
                }
        }
    } else {
#pragma unroll
        for (int jj = 0; jj < 4; ++jj) {
            const int n = n0 + wn * 64 + jj * 16 + ln;
            const int c = n - 2048;                       // channel h*64+d
#pragma unroll
            for (int i = 0; i < 8; ++i) {
                const int m00 = m0 + wm * 128 + i * 16 + quad * 4;  // 4 consecutive tokens
                const int b = m00 >> 11, tt = m00 & 2047;
                ushort4 pk;
                pk.x = f2bf(acc[i][jj][0] + bv[jj]);
                pk.y = f2bf(acc[i][jj][1] + bv[jj]);
                pk.z = f2bf(acc[i][jj][2] + bv[jj]);
                pk.w = f2bf(acc[i][jj][3] + bv[jj]);
                *(ushort4*)&Vtp[(size_t)(b * 1024 + c) * T_SEQ + tt] = pk;
            }
        }
    }
}

// ---------------------------------------------------------------------------
// Kernel: proj GEMM -> fp32 out.  n-tiles on blockIdx.x (XCD L2).
// ---------------------------------------------------------------------------
__global__ __launch_bounds__(256) void proj_gemm(
    const unsigned short* __restrict__ Yin,   // [4096,1024] bf16
    const unsigned short* __restrict__ Wt,    // [1024,1024] bf16 (W^T)
    const float* __restrict__ bias,           // [1024]
    float* __restrict__ out)                  // [4096,1024] fp32
{
    __shared__ unsigned short As[128 * 64];
    __shared__ unsigned short Bs[128 * 64];
    const int m0 = blockIdx.y * 128;
    const int n0 = blockIdx.x * 128;

    f32x4 acc[4][4];
#pragma unroll
    for (int i = 0; i < 4; ++i)
#pragma unroll
        for (int j = 0; j < 4; ++j) acc[i][j] = (f32x4){0.f, 0.f, 0.f, 0.f};

    gemm128_core(Yin, Wt, CDIM, m0, n0, As, Bs, acc);

    const int tid = threadIdx.x;
    const int w = tid >> 6, lane = tid & 63;
    const int ln = lane & 15, quad = lane >> 4;
    const int wm = w >> 1, wn = w & 1;

#pragma unroll
    for (int j = 0; j < 4; ++j) {
        const int n = n0 + wn * 64 + j * 16 + ln;
        const float bv = bias[n];
#pragma unroll
        for (int i = 0; i < 4; ++i)
#pragma unroll
            for (int r = 0; r < 4; ++r) {
                const int m = m0 + wm * 64 + i * 16 + quad * 4 + r;
                out[(size_t)m * CDIM + n] = acc[i][j][r] + bv;
            }
    }
}

// ---------------------------------------------------------------------------
// MFMA flash attention (unchanged)
// ---------------------------------------------------------------------------
#define ATT_STRIDE 72

__global__ __launch_bounds__(256) void flash_attn(
    const unsigned short* __restrict__ Qp,   // [BH, T, 64]
    const unsigned short* __restrict__ Kp,   // [BH, T, 64]
    const unsigned short* __restrict__ Vtp,  // [BH, 64, T]
    const int* __restrict__ mask,            // [B, T]
    unsigned short* __restrict__ Y)          // [B*T, 1024] bf16
{
    __shared__ unsigned short Ks[64 * ATT_STRIDE];
    __shared__ unsigned short Vs[64 * ATT_STRIDE];
    __shared__ unsigned short Ps[64 * ATT_STRIDE];
    __shared__ float mask_f[64];

    const int bh = blockIdx.x;                       // XCD locality on K/V
    const int qt = (T_SEQ / 64 - 1) - blockIdx.y;    // heavy first
    const int b = bh >> 4, h = bh & 15;
    const int tid = threadIdx.x;
    const int w = tid >> 6, lane = tid & 63;
    const int ln = lane & 15, quad = lane >> 4;
    const int row8 = tid >> 3, seg = tid & 7;
    const size_t base = (size_t)bh * T_SEQ * HD;
    const int q0 = qt * 64;

    U16x8 qf[2];
    {
        const unsigned short* qrow = &Qp[base + (size_t)(q0 + w * 16 + ln) * HD];
        qf[0].u4 = *(const uint4*)&qrow[quad * 8];
        qf[1].u4 = *(const uint4*)&qrow[32 + quad * 8];
    }

    f32x4 o[4];
#pragma unroll
    for (int n = 0; n < 4; ++n) o[n] = (f32x4){0.f, 0.f, 0.f, 0.f};
    float m_i[4] = {-3.0e38f, -3.0e38f, -3.0e38f, -3.0e38f};
    float l_i[4] = {0.f, 0.f, 0.f, 0.f};   // per-lane PARTIAL sums

    // register prefetch of tile 0
    uint4 kr0, kr1, vr0, vr1;
    float mf = 0.f;
    {
        const unsigned short* kp0 = &Kp[base + (size_t)row8 * HD + seg * 8];
        kr0 = *(const uint4*)kp0;
        kr1 = *(const uint4*)(kp0 + 32 * HD);
        const unsigned short* vp0 = &Vtp[base + (size_t)row8 * T_SEQ + seg * 8];
        vr0 = *(const uint4*)vp0;
        vr1 = *(const uint4*)(vp0 + 32 * T_SEQ);
        if (tid < 64) mf = mask[b * T_SEQ + tid] ? 0.f : -1.0e30f;
    }

    for (int j = 0; j <= qt; ++j) {
        __syncthreads();
        *(uint4*)&Ks[row8 * ATT_STRIDE + seg * 8] = kr0;
        *(uint4*)&Ks[(row8 + 32) * ATT_STRIDE + seg * 8] = kr1;
        *(uint4*)&Vs[row8 * ATT_STRIDE + seg * 8] = vr0;
        *(uint4*)&Vs[(row8 + 32) * ATT_STRIDE + seg * 8] = vr1;
        if (tid < 64) mask_f[tid] = mf;
        __syncthreads();

        if (j < qt) {   // prefetch next tile
            const unsigned short* kp0 = &Kp[base + (size_t)((j + 1) * 64 + row8) * HD + seg * 8];
            kr0 = *(const uint4*)kp0;
            kr1 = *(const uint4*)(kp0 + 32 * HD);
            const unsigned short* vp0 = &Vtp[base + (size_t)row8 * T_SEQ + (j + 1) * 64 + seg * 8];
            vr0 = *(const uint4*)vp0;
            vr1 = *(const uint4*)(vp0 + 32 * T_SEQ);
            if (tid < 64) mf = mask[b * T_SEQ + (j + 1) * 64 + tid] ? 0.f : -1.0e30f;
        }

        const bool diag = (j == qt);

        // S = Q K^T
        f32x4 sc[4];
#pragma unroll
        for (int t = 0; t < 4; ++t) sc[t] = (f32x4){0.f, 0.f, 0.f, 0.f};
#pragma unroll
        for (int t = 0; t < 4; ++t) {
            if (diag && t > w) continue;
#pragma unroll
            for (int s = 0; s < 2; ++s) {
                U16x8 kb;
                kb.u4 = *(const uint4*)&Ks[(t * 16 + ln) * ATT_STRIDE + s * 32 + quad * 8];
                sc[t] = __builtin_amdgcn_mfma_f32_16x16x32_bf16(qf[s].b, kb.b, sc[t], 0, 0, 0);
            }
        }

        // pass 1: scale + additive mask + row max
        float rm[4] = {-3.0e38f, -3.0e38f, -3.0e38f, -3.0e38f};
#pragma unroll
        for (int t = 0; t < 4; ++t) {
            if (diag && t > w) {
#pragma unroll
                for (int i = 0; i < 4; ++i) sc[t][i] = -1.0e30f;
            } else {
                const float madd = mask_f[t * 16 + ln];
                const bool edge = diag && (t == w);
#pragma unroll
                for (int i = 0; i < 4; ++i) {
                    float v = fmaf(sc[t][i], 0.125f, madd);
                    if (edge && ln > quad * 4 + i) v = -1.0e30f;
                    sc[t][i] = v;
                    rm[i] = fmaxf(rm[i], v);
                }
            }
        }
#pragma unroll
        for (int i = 0; i < 4; ++i) {
            rm[i] = fmaxf(rm[i], __shfl_xor(rm[i], 1));
            rm[i] = fmaxf(rm[i], __shfl_xor(rm[i], 2));
            rm[i] = fmaxf(rm[i], __shfl_xor(rm[i], 4));
            rm[i] = fmaxf(rm[i], __shfl_xor(rm[i], 8));
        }

        // pass 2: alpha, exp2, per-lane partial sum
        float alpha[4], mlog[4];
#pragma unroll
        for (int i = 0; i < 4; ++i) {
            const float nm = fmaxf(m_i[i], rm[i]);
            alpha[i] = __builtin_amdgcn_exp2f((m_i[i] - nm) * LOG2E);
            m_i[i] = nm;
            mlog[i] = nm * LOG2E;
        }
        float rsp[4] = {0.f, 0.f, 0.f, 0.f};
#pragma unroll
        for (int t = 0; t < 4; ++t)
#pragma unroll
            for (int i = 0; i < 4; ++i) {
                const float p = __builtin_amdgcn_exp2f(fmaf(sc[t][i], LOG2E, -mlog[i]));
                sc[t][i] = p;
                rsp[i] += p;
            }
#pragma unroll
        for (int i = 0; i < 4; ++i) l_i[i] = l_i[i] * alpha[i] + rsp[i];
#pragma unroll
        for (int n = 0; n < 4; ++n)
#pragma unroll
            for (int i = 0; i < 4; ++i) o[n][i] *= alpha[i];

        // P -> LDS -> A-frags
#pragma unroll
        for (int t = 0; t < 4; ++t)
#pragma unroll
            for (int i = 0; i < 4; ++i)
                Ps[(w * 16 + quad * 4 + i) * ATT_STRIDE + t * 16 + ln] = f2bf_fast(sc[t][i]);

        U16x8 pa[2];
        pa[0].u4 = *(const uint4*)&Ps[(w * 16 + ln) * ATT_STRIDE + quad * 8];
        pa[1].u4 = *(const uint4*)&Ps[(w * 16 + ln) * ATT_STRIDE + 32 + quad * 8];

        // O += P V
#pragma unroll
        for (int n = 0; n < 4; ++n)
#pragma unroll
            for (int s = 0; s < 2; ++s) {
                U16x8 vb;
                vb.u4 = *(const uint4*)&Vs[(n * 16 + ln) * ATT_STRIDE + s * 32 + quad * 8];
                o[n] = __builtin_amdgcn_mfma_f32_16x16x32_bf16(pa[s].b, vb.b, o[n], 0, 0, 0);
            }
    }

    // epilogue: reduce partial l across the 16 row-lanes, normalize, store
#pragma unroll
    for (int i = 0; i < 4; ++i) {
        float l = l_i[i];
        l += __shfl_xor(l, 1);
        l += __shfl_xor(l, 2);
        l += __shfl_xor(l, 4);
        l += __shfl_xor(l, 8);
        const float inv = 1.0f / l;
        const size_t row = (size_t)(b * T_SEQ + q0 + w * 16 + quad * 4 + i);
#pragma unroll
        for (int n = 0; n < 4; ++n)
            Y[row * CDIM + h * HD + n * 16 + ln] = f2bf(o[n][i] * inv);
    }
}

// ---------------------------------------------------------------------------
extern "C" void kernel_launch(void* const* d_in, const int* in_sizes, int n_in,
                              void* d_out, int out_size, void* d_ws, size_t ws_size,
                              hipStream_t stream)
{
    const float* X     = (const float*)d_in[0];
    const int*   mask  = (const int*)d_in[1];
    const float* Wqkv  = (const float*)d_in[2];
    const float* bqkv  = (const float*)d_in[3];
    const float* Wproj = (const float*)d_in[4];
    const float* bproj = (const float*)d_in[5];
    float* out = (float*)d_out;

    const size_t per = (size_t)2 * NHEAD * T_SEQ * HD;   // 4,194,304 elems
    unsigned short* Qp     = (unsigned short*)d_ws;
    unsigned short* Kp     = Qp + per;
    unsigned short* Vtp    = Kp + per;
    unsigned short* Xb     = Vtp + per;                  // aliased: Yp reuses Xb
    unsigned short* Yp     = Xb;                         // X consumed before Y written
    unsigned short* Wqkvt  = Xb + per;                   // [3072,1024]
    unsigned short* Wprojt = Wqkvt + (size_t)3 * CDIM * CDIM;  // [1024,1024]

    conv_bf16<<<2048, 256, 0, stream>>>(X, Xb, 4 * 1024 * 1024);
    transpose_conv<<<dim3(16, 48), 256, 0, stream>>>(Wqkv, Wqkvt, CDIM, 3 * CDIM);
    transpose_conv<<<dim3(16, 16), 256, 0, stream>>>(Wproj, Wprojt, CDIM, CDIM);

    qkv8<<<192, 512, 0, stream>>>(Xb, Wqkvt, bqkv, Qp, Kp, Vtp);
    flash_attn<<<dim3(2 * NHEAD, T_SEQ / 64), 256, 0, stream>>>(Qp, Kp, Vtp, mask, Yp);
    proj_gemm<<<dim3(8, 32), 256, 0, stream>>>(Yp, Wprojt, bproj, out);
}